// Round 2
// 521.521 us; speedup vs baseline: 1.0548x; 1.0548x over previous
//
#include <hip/hip_runtime.h>

// ---------------------------------------------------------------------------
// QuantumQLSTM: analytic collapse of the quantum circuit.
//   ang[g][b][n] = W_g[n,:256]·x + W_g[n,256:264]·hx + bias_g[n] + theta_g[n]
//   m[g][b][0]   = prod_{j=1..7} cos(ang[g][b][j])
//   m[g][b][n>0] = prod_{j=0..n} cos(ang[g][b][j])
// then a standard LSTM cell update.
// ---------------------------------------------------------------------------

#define BQ   512   // batch
#define TT   512   // timesteps
#define IND  256   // input dim
#define PRE_OFF 8704  // float offset of pre[] inside ws

// ws float layout:
//   [0, 8192)        Wt[d][gn]   (256 x 32)  x-part of W, transposed
//   [8192, 8448)     Wh[gn][j]   (32 x 8)    h-part of W
//   [8448, 8480)     C[gn]                    bias + theta
//   [8704, 8704+8388608)  pre[b][t/4][gn][4]  (B*T*32 floats)

__global__ void prep_kernel(const float* __restrict__ Wf, const float* __restrict__ bf,
                            const float* __restrict__ Wi, const float* __restrict__ bi,
                            const float* __restrict__ Wg, const float* __restrict__ bg,
                            const float* __restrict__ Wo, const float* __restrict__ bo,
                            const float* __restrict__ th, float* __restrict__ wsf) {
    const float* W[4]    = {Wf, Wi, Wg, Wo};
    const float* bias[4] = {bf, bi, bg, bo};
    int d = threadIdx.x;  // 0..255
    for (int g = 0; g < 4; g++)
        for (int n = 0; n < 8; n++)
            wsf[d * 32 + g * 8 + n] = W[g][n * 264 + d];
    if (d < 32) {
        int g = d >> 3, n = d & 7;
        for (int j = 0; j < 8; j++)
            wsf[8192 + d * 8 + j] = W[g][n * 264 + 256 + j];
        wsf[8448 + d] = bias[g][n] + th[d];
    }
}

// ---------------------------------------------------------------------------
// pre_gemm v2: LDS-staged coalesced x reads.
//   Old version: lane i read row i as 64 sequential float4 -> every VMEM
//   instruction touched 64 distinct cache lines (16B/line used) ->
//   transaction-bound at 2.4 TB/s, 1.4x over-fetch from L1 thrash.
//   New: block stages a 256-row x 32-K chunk into LDS with coalesced float4
//   loads (8 contiguous 128B segments per wave instr, lines fully used),
//   register-prefetches the next chunk under the FMA phase, then each thread
//   reads its own row from LDS.
//   LDS stride 33 floats: bank = (33*row + k) % 32 = (row + k) % 32 ->
//   exactly 2 lanes/bank for a wave64 read = conflict-free (2-way is free).
//   Staging writes: bank = (row + 4*k4 + c) % 32, row in [rB,rB+7],
//   4*k4 in {0..28}: each residue hit exactly twice -> also conflict-free.
//   33 KB LDS -> 4 blocks/CU -> 16 waves/CU to overlap barrier phases.
// ---------------------------------------------------------------------------

#define ROWS 256   // bt rows per block (= threads)
#define KC   32    // K-chunk width
#define NCH  (IND / KC)   // 8 chunks
#define LSTR 33    // padded LDS row stride (floats)

__global__ __launch_bounds__(256, 4) void pre_gemm(const float* __restrict__ x,
                                                   const float* __restrict__ wsf,
                                                   float* __restrict__ pre) {
    __shared__ float tile[ROWS * LSTR];   // 33792 B
    const int tid  = threadIdx.x;
    const int row0 = blockIdx.x * ROWS;

    const float* cvec = wsf + 8448;
    float acc[32];
#pragma unroll
    for (int k = 0; k < 32; k++) acc[k] = cvec[k];

    // Staging assignment: linear = it*256 + tid; srow = linear>>3; sk4 = linear&7.
    // Per chunk each thread loads 8 float4 (coalesced) and writes them to LDS.
    float4 R[8];
#pragma unroll
    for (int it = 0; it < 8; it++) {
        int linear = it * 256 + tid;
        int srow = linear >> 3, sk4 = linear & 7;
        R[it] = *(const float4*)(x + (size_t)(row0 + srow) * IND + sk4 * 4);
    }

#pragma unroll 1
    for (int c = 0; c < NCH; c++) {
        __syncthreads();   // previous compute phase done -> LDS reusable
#pragma unroll
        for (int it = 0; it < 8; it++) {
            int linear = it * 256 + tid;
            int srow = linear >> 3, sk4 = linear & 7;
            float* d = tile + srow * LSTR + sk4 * 4;
            d[0] = R[it].x; d[1] = R[it].y; d[2] = R[it].z; d[3] = R[it].w;
        }
        if (c + 1 < NCH) {
            // issue next chunk's global loads now; latency hides under FMAs
#pragma unroll
            for (int it = 0; it < 8; it++) {
                int linear = it * 256 + tid;
                int srow = linear >> 3, sk4 = linear & 7;
                R[it] = *(const float4*)(x + (size_t)(row0 + srow) * IND
                                           + (c + 1) * KC + sk4 * 4);
            }
        }
        __syncthreads();   // tile ready
        const float* xr = tile + tid * LSTR;
        const float* wb = wsf + c * KC * 32;   // uniform -> scalar loads
#pragma unroll
        for (int k = 0; k < KC; k++) {
            float xk = xr[k];
            const float* wr = wb + k * 32;
#pragma unroll
            for (int kk = 0; kk < 32; kk++) acc[kk] = fmaf(xk, wr[kk], acc[kk]);
        }
    }

    const int bt = row0 + tid;
    const int b = bt >> 9, t = bt & 511, t4 = t >> 2, tm = t & 3;
    float* dst = pre + ((size_t)(b * 128 + t4)) * 128 + tm;
#pragma unroll
    for (int k = 0; k < 32; k++) dst[k * 4] = acc[k];
}

#define SWZ(x, imm) __int_as_float(__builtin_amdgcn_ds_swizzle(__float_as_int(x), (imm)))

template <int CTRL>
__device__ __forceinline__ float dpp_shr(float x) {
    // row_shr within 16-lane rows; OOB lanes get 0 (guarded by caller).
    return __int_as_float(__builtin_amdgcn_update_dpp(
        0, __float_as_int(x), CTRL, 0xF, 0xF, true));
}

__global__ __launch_bounds__(64) void recur(const float* __restrict__ wsf,
                                            float* __restrict__ out) {
    const int lane = threadIdx.x;        // 0..63 (one wave)
    const int l32  = lane & 31;          // lane within 32-lane batch group
    const int half = lane >> 5;
    const int b    = blockIdx.x * 2 + half;
    const int g    = l32 >> 3;           // gate 0..3 (f,i,g,o)
    const int n    = l32 & 7;            // qubit / hidden index

    float whr[8];
#pragma unroll
    for (int j = 0; j < 8; j++) whr[j] = wsf[8192 + l32 * 8 + j];

    const float4* pp = (const float4*)(wsf + PRE_OFF) + (size_t)b * 128 * 32 + l32;

    float hx[8];
#pragma unroll
    for (int j = 0; j < 8; j++) hx[j] = 0.0f;
    float cx = 0.0f;

    float4 bufA = pp[0];
    float4 bufB = pp[32];

    float* outp = out + (size_t)b * TT * 8 + n;
    const float L2E = 1.4426950408889634f;

    for (int t4 = 0; t4 < 128; t4++) {
        float4 cur = (t4 & 1) ? bufB : bufA;
        int nx = (t4 + 2 < 128) ? (t4 + 2) : 127;
        if (t4 & 1) bufB = pp[(size_t)nx * 32];
        else        bufA = pp[(size_t)nx * 32];
        float pv4[4] = {cur.x, cur.y, cur.z, cur.w};
#pragma unroll
        for (int tm = 0; tm < 4; tm++) {
            float ang = pv4[tm];
#pragma unroll
            for (int j = 0; j < 8; j++) ang = fmaf(whr[j], hx[j], ang);
            float c = __cosf(ang);
            // inclusive prefix product of e (c with lane n==0 replaced by 1)
            float s = (n == 0) ? 1.0f : c;
            { float v = dpp_shr<0x111>(s); s = (n >= 1) ? s * v : s; }
            { float v = dpp_shr<0x112>(s); s = (n >= 2) ? s * v : s; }
            { float v = dpp_shr<0x114>(s); s = (n >= 4) ? s * v : s; }
            float c0 = SWZ(c, 0x018);   // cos of qubit 0 within this gate group
            float s7 = SWZ(s, 0x0F8);   // prod_{1..7}
            float m  = (n == 0) ? s7 : c0 * s;
            // f,i,o: sigmoid(m); g: tanh(m) = 2*sigmoid(2m)-1
            float kk  = (g == 2) ? (-2.0f * L2E) : (-L2E);
            float u   = __builtin_amdgcn_rcpf(1.0f + __builtin_amdgcn_exp2f(m * kk));
            float val = (g == 2) ? fmaf(2.0f, u, -1.0f) : u;
            float fv = SWZ(val, 0x007);
            float iv = SWZ(val, 0x107);
            float gv = SWZ(val, 0x207);
            float ov = SWZ(val, 0x307);
            cx = fmaf(fv, cx, iv * gv);
            float t2 = __builtin_amdgcn_exp2f(cx * (-2.0f * L2E));
            float th = fmaf(2.0f, __builtin_amdgcn_rcpf(1.0f + t2), -1.0f);
            float hxn = ov * th;
            if (l32 < 8) outp[(t4 * 4 + tm) * 8] = hxn;
            // broadcast new hx[0..7] to every lane (from own gate group's copies)
            hx[0] = SWZ(hxn, 0x018);
            hx[1] = SWZ(hxn, 0x038);
            hx[2] = SWZ(hxn, 0x058);
            hx[3] = SWZ(hxn, 0x078);
            hx[4] = SWZ(hxn, 0x098);
            hx[5] = SWZ(hxn, 0x0B8);
            hx[6] = SWZ(hxn, 0x0D8);
            hx[7] = SWZ(hxn, 0x0F8);
        }
    }
    if (l32 < 8) {
        out[(size_t)BQ * TT * 8 + b * 8 + n]            = hx[n];
        out[(size_t)BQ * TT * 8 + BQ * 8 + b * 8 + n]   = cx;
    }
}

extern "C" void kernel_launch(void* const* d_in, const int* in_sizes, int n_in,
                              void* d_out, int out_size, void* d_ws, size_t ws_size,
                              hipStream_t stream) {
    const float* x  = (const float*)d_in[0];
    const float* Wf = (const float*)d_in[1];
    const float* bf = (const float*)d_in[2];
    const float* Wi = (const float*)d_in[3];
    const float* bi = (const float*)d_in[4];
    const float* Wg = (const float*)d_in[5];
    const float* bg = (const float*)d_in[6];
    const float* Wo = (const float*)d_in[7];
    const float* bo = (const float*)d_in[8];
    const float* th = (const float*)d_in[9];
    float* wsf = (float*)d_ws;
    float* out = (float*)d_out;

    prep_kernel<<<1, 256, 0, stream>>>(Wf, bf, Wi, bi, Wg, bg, Wo, bo, th, wsf);
    pre_gemm<<<(BQ * TT) / 256, 256, 0, stream>>>(x, wsf, wsf + PRE_OFF);
    recur<<<BQ / 2, 64, 0, stream>>>(wsf, out);
}